// Round 6
// baseline (532.560 us; speedup 1.0000x reference)
//
#include <hip/hip_runtime.h>
#include <hip/hip_bf16.h>

#define GN_EPS 1e-5f

__device__ __forceinline__ unsigned short f2bf(float f) {
    unsigned u = __float_as_uint(f);
    u += 0x7fffu + ((u >> 16) & 1u);   // round-to-nearest-even
    return (unsigned short)(u >> 16);
}

// ---------------- CSR build ----------------
__global__ void k_degi(const int* __restrict__ dst, int* __restrict__ degi, int e) {
    int i = blockIdx.x * blockDim.x + threadIdx.x;
    if (i < e) atomicAdd(&degi[dst[i]], 1);
}

// 3-phase multi-block exclusive scan of degi (chunk = 4096 = 256 thr x 16)
#define SCAN_CHUNK 4096
__global__ __launch_bounds__(256) void k_blocksum(const int* __restrict__ degi,
                                                  int* __restrict__ partial, int n) {
    int base = blockIdx.x * SCAN_CHUNK + threadIdx.x * 16;
    int s = 0;
    #pragma unroll
    for (int q = 0; q < 16; ++q) {
        int i = base + q;
        if (i < n) s += degi[i];
    }
    #pragma unroll
    for (int off = 32; off; off >>= 1) s += __shfl_down(s, off);
    __shared__ int ws[4];
    if ((threadIdx.x & 63) == 0) ws[threadIdx.x >> 6] = s;
    __syncthreads();
    if (threadIdx.x == 0) partial[blockIdx.x] = ws[0] + ws[1] + ws[2] + ws[3];
}

__global__ void k_scanpart(int* __restrict__ partial, int* __restrict__ rowptr,
                           int nb, int n) {
    if (threadIdx.x == 0) {
        int acc = 0;
        for (int i = 0; i < nb; ++i) { int v = partial[i]; partial[i] = acc; acc += v; }
        rowptr[n] = acc;
    }
}

__global__ __launch_bounds__(256) void k_scanfinal(const int* __restrict__ degi,
                                                   const int* __restrict__ partial,
                                                   int* __restrict__ rowptr,
                                                   int* __restrict__ cursor,
                                                   float* __restrict__ dinv, int n) {
    int base = blockIdx.x * SCAN_CHUNK + threadIdx.x * 16;
    int v[16];
    int s = 0;
    #pragma unroll
    for (int q = 0; q < 16; ++q) {
        int i = base + q;
        v[q] = (i < n) ? degi[i] : 0;
        s += v[q];
    }
    const int lane = threadIdx.x & 63;
    const int wid = threadIdx.x >> 6;
    int x = s;
    #pragma unroll
    for (int off = 1; off < 64; off <<= 1) {
        int t = __shfl_up(x, off);
        if (lane >= off) x += t;
    }
    __shared__ int ws[4];
    if (lane == 63) ws[wid] = x;
    __syncthreads();
    int waveoff = 0;
    if (wid > 0) waveoff += ws[0];
    if (wid > 1) waveoff += ws[1];
    if (wid > 2) waveoff += ws[2];
    int excl = x - s + waveoff + partial[blockIdx.x];
    #pragma unroll
    for (int q = 0; q < 16; ++q) {
        int i = base + q;
        if (i < n) {
            rowptr[i] = excl;
            cursor[i] = excl;
            dinv[i] = rsqrtf((float)(v[q] + 1));
        }
        excl += v[q];
    }
}

__global__ void k_fill(const int* __restrict__ src, const int* __restrict__ dst,
                       int* __restrict__ cursor, int* __restrict__ csr_src, int e) {
    int i = blockIdx.x * blockDim.x + threadIdx.x;
    if (i < e) {
        int d = dst[i];
        int pos = atomicAdd(&cursor[d], 1);
        csr_src[pos] = src[i];
    }
}

// ---------------- GEMM: Ybf16[n,128] = f(X)[n,128] @ W[128,128] ----------------
// Column-split: block = 64 rows x 64 cols. sW 32KB + sx 33KB -> 2 blocks/CU.
#define TM 64
__global__ __launch_bounds__(256) void k_gemm128(const float* __restrict__ X,
                                                 const float* __restrict__ W,
                                                 unsigned short* __restrict__ Y,
                                                 const float* __restrict__ cs,
                                                 const float* __restrict__ cb,
                                                 int nrows) {
    __shared__ float sW[128 * 64];
    __shared__ float sx[TM * 129];
    const int t = threadIdx.x;
    const int c0 = blockIdx.y * 64;

    for (int i = t; i < 128 * 16; i += 256) {
        int k = i >> 4;
        int f4 = i & 15;
        ((float4*)(sW + k * 64))[f4] = ((const float4*)(W + (size_t)k * 128 + c0))[f4];
    }
    const int row0 = blockIdx.x * TM;
    if (cs) {
        for (int i = t; i < TM * 32; i += 256) {
            int r = i >> 5, c4 = i & 31;
            int grow = row0 + r;
            float4 v = make_float4(0.f, 0.f, 0.f, 0.f);
            if (grow < nrows) v = ((const float4*)(X + (size_t)grow * 128))[c4];
            float4 s4 = ((const float4*)cs)[c4];
            float4 b4 = ((const float4*)cb)[c4];
            v.x = fmaxf(fmaf(v.x, s4.x, b4.x), 0.f);
            v.y = fmaxf(fmaf(v.y, s4.y, b4.y), 0.f);
            v.z = fmaxf(fmaf(v.z, s4.z, b4.z), 0.f);
            v.w = fmaxf(fmaf(v.w, s4.w, b4.w), 0.f);
            float* d = &sx[r * 129 + c4 * 4];
            d[0] = v.x; d[1] = v.y; d[2] = v.z; d[3] = v.w;
        }
    } else {
        for (int i = t; i < TM * 32; i += 256) {
            int r = i >> 5, c4 = i & 31;
            int grow = row0 + r;
            float4 v = make_float4(0.f, 0.f, 0.f, 0.f);
            if (grow < nrows) v = ((const float4*)(X + (size_t)grow * 128))[c4];
            float* d = &sx[r * 129 + c4 * 4];
            d[0] = v.x; d[1] = v.y; d[2] = v.z; d[3] = v.w;
        }
    }
    __syncthreads();

    const int tc = t & 15;
    const int tr = t >> 4;
    float acc[4][4] = {};
    #pragma unroll 4
    for (int k = 0; k < 128; ++k) {
        float4 w = *(const float4*)(sW + k * 64 + tc * 4);
        float x0 = sx[(tr * 4 + 0) * 129 + k];
        float x1 = sx[(tr * 4 + 1) * 129 + k];
        float x2 = sx[(tr * 4 + 2) * 129 + k];
        float x3 = sx[(tr * 4 + 3) * 129 + k];
        acc[0][0] += x0 * w.x; acc[0][1] += x0 * w.y; acc[0][2] += x0 * w.z; acc[0][3] += x0 * w.w;
        acc[1][0] += x1 * w.x; acc[1][1] += x1 * w.y; acc[1][2] += x1 * w.z; acc[1][3] += x1 * w.w;
        acc[2][0] += x2 * w.x; acc[2][1] += x2 * w.y; acc[2][2] += x2 * w.z; acc[2][3] += x2 * w.w;
        acc[3][0] += x3 * w.x; acc[3][1] += x3 * w.y; acc[3][2] += x3 * w.z; acc[3][3] += x3 * w.w;
    }
    #pragma unroll
    for (int i = 0; i < 4; ++i) {
        int grow = row0 + tr * 4 + i;
        if (grow >= nrows) continue;
        ushort4 o;
        o.x = f2bf(acc[i][0]); o.y = f2bf(acc[i][1]);
        o.z = f2bf(acc[i][2]); o.w = f2bf(acc[i][3]);
        *(ushort4*)(Y + (size_t)grow * 128 + c0 + tc * 4) = o;
    }
}

// ---------------- pull-gather conv (bf16 input, fp32 output) ----------------
__global__ __launch_bounds__(256) void k_gather(const unsigned short* __restrict__ H,
                                                float* __restrict__ O,
                                                const int* __restrict__ rowptr,
                                                const int* __restrict__ csr_src,
                                                const float* __restrict__ dinv,
                                                const float* __restrict__ bias, int n) {
    int node = blockIdx.x * 4 + (threadIdx.x >> 6);
    if (node >= n) return;
    int lane = threadIdx.x & 63;
    const unsigned* H2 = (const unsigned*)H;
    float di = dinv[node];
    unsigned hu = H2[(size_t)node * 64 + lane];
    float2 b = ((const float2*)bias)[lane];
    float2 acc;
    acc.x = __uint_as_float(hu << 16)         * di * di + b.x;
    acc.y = __uint_as_float(hu & 0xffff0000u) * di * di + b.y;
    int j = rowptr[node];
    const int end = rowptr[node + 1];
    for (; j + 7 < end; j += 8) {
        int s[8];
        #pragma unroll
        for (int q = 0; q < 8; ++q) s[q] = csr_src[j + q];
        unsigned u[8];
        float nr[8];
        #pragma unroll
        for (int q = 0; q < 8; ++q) {
            u[q] = H2[(size_t)s[q] * 64 + lane];
            nr[q] = dinv[s[q]] * di;
        }
        #pragma unroll
        for (int q = 0; q < 8; ++q) {
            acc.x += __uint_as_float(u[q] << 16)         * nr[q];
            acc.y += __uint_as_float(u[q] & 0xffff0000u) * nr[q];
        }
    }
    for (; j < end; ++j) {
        int s = csr_src[j];
        float nn = dinv[s] * di;
        unsigned u = H2[(size_t)s * 64 + lane];
        acc.x += __uint_as_float(u << 16)         * nn;
        acc.y += __uint_as_float(u & 0xffff0000u) * nn;
    }
    ((float2*)(O + (size_t)node * 128))[lane] = acc;
}

// ---------------- GraphNorm stats + folded finstats (last-block) ----------------
__global__ __launch_bounds__(256) void k_stats(const float* __restrict__ H,
                                               float* __restrict__ S,
                                               int* __restrict__ done,
                                               const float* __restrict__ w,
                                               const float* __restrict__ b,
                                               const float* __restrict__ alpha,
                                               float* __restrict__ colscale,
                                               float* __restrict__ colshift, int n) {
    int c = threadIdx.x & 127;
    int half = threadIdx.x >> 7;
    float sum = 0.f, ss = 0.f;
    for (int r = blockIdx.x * 2 + half; r < n; r += gridDim.x * 2) {
        float v = H[(size_t)r * 128 + c];
        sum += v;
        ss += v * v;
    }
    __shared__ float ls[256], lss[256];
    ls[threadIdx.x] = sum;
    lss[threadIdx.x] = ss;
    __syncthreads();
    if (threadIdx.x < 128) {
        atomicAdd(&S[c],       ls[threadIdx.x] + ls[threadIdx.x + 128]);
        atomicAdd(&S[128 + c], lss[threadIdx.x] + lss[threadIdx.x + 128]);
    }
    __syncthreads();           // all S-atomics of this block issued
    __threadfence();
    __shared__ int isLast;
    if (threadIdx.x == 0) isLast = (atomicAdd(done, 1) == (int)gridDim.x - 1);
    __syncthreads();
    if (isLast && threadIdx.x < 128) {
        float sv = atomicAdd(&S[c], 0.0f);        // atomic load
        float sq = atomicAdd(&S[128 + c], 0.0f);
        float inv_n = 1.0f / (float)n;
        float m = sv * inv_n;
        float eh2 = sq * inv_n;
        float a = alpha[c];
        float var = eh2 - (2.0f * a - a * a) * m * m;
        float scale = rsqrtf(var + GN_EPS) * w[c];
        colscale[c] = scale;
        colshift[c] = b[c] - a * m * scale;
    }
}

// ---------------- output projection ----------------
__global__ __launch_bounds__(256) void k_outproj(const float* __restrict__ H,
                                                 const float* __restrict__ Wo,
                                                 const float* __restrict__ bo,
                                                 float* __restrict__ out, int n) {
    int row = blockIdx.x * (blockDim.x >> 6) + (threadIdx.x >> 6);
    if (row >= n) return;
    int lane = threadIdx.x & 63;
    const float* hr = H + (size_t)row * 128;
    float h0 = hr[lane], h1 = hr[lane + 64];
    float a0 = h0 * Wo[2 * lane]     + h1 * Wo[2 * (lane + 64)];
    float a1 = h0 * Wo[2 * lane + 1] + h1 * Wo[2 * (lane + 64) + 1];
    #pragma unroll
    for (int off = 32; off; off >>= 1) {
        a0 += __shfl_down(a0, off);
        a1 += __shfl_down(a1, off);
    }
    if (lane == 0) {
        out[(size_t)row * 2]     = a0 + bo[0];
        out[(size_t)row * 2 + 1] = a1 + bo[1];
    }
}

extern "C" void kernel_launch(void* const* d_in, const int* in_sizes, int n_in,
                              void* d_out, int out_size, void* d_ws, size_t ws_size,
                              hipStream_t stream) {
    const float* x    = (const float*)d_in[0];
    const int*   ei   = (const int*)  d_in[1];
    const float* W1   = (const float*)d_in[2];
    const float* b1   = (const float*)d_in[3];
    const float* W2   = (const float*)d_in[4];
    const float* b2   = (const float*)d_in[5];
    const float* W3   = (const float*)d_in[6];
    const float* b3   = (const float*)d_in[7];
    const float* gn1w = (const float*)d_in[8];
    const float* gn1b = (const float*)d_in[9];
    const float* gn1a = (const float*)d_in[10];
    const float* gn2w = (const float*)d_in[11];
    const float* gn2b = (const float*)d_in[12];
    const float* gn2a = (const float*)d_in[13];
    const float* Wout = (const float*)d_in[14];
    const float* bout = (const float*)d_in[15];
    float* out = (float*)d_out;

    const int n = in_sizes[0] / 128;
    const int e = in_sizes[1] / 2;
    const int* srcI = ei;
    const int* dstI = ei + e;

    float* bufB     = (float*)d_ws;                                   // n*128 fp32
    unsigned short* bufH = (unsigned short*)(bufB + (size_t)n * 128); // n*128 bf16
    float* dinv     = (float*)(bufH + (size_t)n * 128);               // n
    float* colscale = dinv + n;                                       // 128
    float* colshift = colscale + 128;                                 // 128
    // ---- zeroed region (single memset): degi | S1 | S2 | done[2] ----
    int*   degi     = (int*)(colshift + 128);                         // n
    float* S1       = (float*)(degi + n);                             // 256
    float* S2       = S1 + 256;                                       // 256
    int*   done     = (int*)(S2 + 256);                               // 2
    // ---- rest ----
    int*   rowptr   = done + 2;                                       // n+1
    int*   cursor   = rowptr + n + 1;                                 // n
    int*   partial  = cursor + n;                                     // 64
    int*   csr_src  = partial + 64;                                   // e

    const int nb = (n + SCAN_CHUNK - 1) / SCAN_CHUNK;

    // ---- CSR build ----
    hipMemsetAsync(degi, 0, ((size_t)n + 514) * sizeof(int), stream);
    k_degi<<<(e + 255) / 256, 256, 0, stream>>>(dstI, degi, e);
    k_blocksum<<<nb, 256, 0, stream>>>(degi, partial, n);
    k_scanpart<<<1, 64, 0, stream>>>(partial, rowptr, nb, n);
    k_scanfinal<<<nb, 256, 0, stream>>>(degi, partial, rowptr, cursor, dinv, n);
    k_fill<<<(e + 255) / 256, 256, 0, stream>>>(srcI, dstI, cursor, csr_src, e);

    const dim3 gemmGrid((n + TM - 1) / TM, 2);

    // layer 1
    k_gemm128<<<gemmGrid, 256, 0, stream>>>(x, W1, bufH, nullptr, nullptr, n);
    k_gather<<<(n + 3) / 4, 256, 0, stream>>>(bufH, bufB, rowptr, csr_src, dinv, b1, n);
    k_stats<<<512, 256, 0, stream>>>(bufB, S1, done, gn1w, gn1b, gn1a, colscale, colshift, n);

    // layer 2
    k_gemm128<<<gemmGrid, 256, 0, stream>>>(bufB, W2, bufH, colscale, colshift, n);
    k_gather<<<(n + 3) / 4, 256, 0, stream>>>(bufH, bufB, rowptr, csr_src, dinv, b2, n);
    k_stats<<<512, 256, 0, stream>>>(bufB, S2, done + 1, gn2w, gn2b, gn2a, colscale, colshift, n);

    // layer 3 + projection
    k_gemm128<<<gemmGrid, 256, 0, stream>>>(bufB, W3, bufH, colscale, colshift, n);
    k_gather<<<(n + 3) / 4, 256, 0, stream>>>(bufH, bufB, rowptr, csr_src, dinv, b3, n);
    k_outproj<<<(n + 3) / 4, 256, 0, stream>>>(bufB, Wout, bout, out, n);
}